// Round 7
// baseline (169.364 us; speedup 1.0000x reference)
//
#include <hip/hip_runtime.h>
#include <hip/hip_cooperative_groups.h>

namespace cg = cooperative_groups;

// File-wide: every FP op individually rounded (no FMA contraction) so the
// f32 chain (subs, muls, adds) matches numpy op-for-op, bit-exactly.
#pragma clang fp contract(off)

// Exact decision boundary for  RN_f32(inter/uni) > (float)0.7 :
//   c = 0.7f = 0x3f333333, succ(c) = 0x3f333334 (even mantissa).
//   RN(x) > c  <=>  x >= M  where M = (c + succ(c))/2 (tie rounds to even
//   = succ(c) > c, so ">=" is correct).  M = 23488103 * 2^-25 (25 sig bits),
//   uni has <=24 sig bits  =>  M*(double)uni is EXACT, comparison is exact.
//   uni >= 2 always here (every box area >= 1), so uni==0 never occurs.
#define M_BOUND 0.7000000178813934326171875

__device__ __forceinline__ unsigned long long make_key(unsigned int sbits,
                                                       unsigned int idx) {
    // descending score, ascending index tie-break (stable argsort(-score))
    return (((unsigned long long)(~sbits)) << 32) | idx;
}

// ---------------------------------------------------------------------------
// Single cooperative kernel, grid = 512 blocks x 256 threads (2 blocks/CU).
// Phase 1: rank partials (LDS-staged tile, 2 keys/thread, no atomics)
// Phase 2: reduce ranks + scatter box/area + zero mask
// Phase 3: suppress over 528 triangular tile-pairs (grid-stride),
//          branchless f32 body + __any-gated exact f64 boundary compare
// Phase 4: masked output write
// ---------------------------------------------------------------------------
__global__ __launch_bounds__(256, 2)
void nms_fused(const float* __restrict__ score,
               const float4* __restrict__ bbox,
               unsigned int* __restrict__ partial,
               float4* __restrict__ sortedBox,
               float* __restrict__ sortedArea,
               unsigned int* __restrict__ mask,
               float* __restrict__ out,
               int N, int nTiles)
{
    __shared__ __align__(16) char smem_raw[256 * 16 + 256 * 4];
    const int tid = threadIdx.x;
    const int b   = blockIdx.x;
    cg::grid_group grid = cg::this_grid();

    // ---------------- Phase 1: rank partials ----------------
    {
        unsigned long long* skeys = (unsigned long long*)smem_raw;
        const int XB = N / 512;               // 16 x-blocks
        const int bx = b % XB;
        const int y  = b / XB;                // 32 y-tiles
        const int t  = y * 256 + tid;
        skeys[tid] = make_key(__float_as_uint(score[t]), (unsigned int)t);

        const int i0 = bx * 512 + tid;
        const unsigned long long k0 =
            make_key(__float_as_uint(score[i0      ]), i0      );
        const unsigned long long k1 =
            make_key(__float_as_uint(score[i0 + 256]), i0 + 256);
        __syncthreads();

        unsigned int c0 = 0, c1 = 0;
        #pragma unroll 16
        for (int k = 0; k < 256; ++k) {
            const unsigned long long ok = skeys[k];
            c0 += (ok < k0) ? 1u : 0u;
            c1 += (ok < k1) ? 1u : 0u;
        }
        unsigned int* row = partial + (size_t)y * N;
        row[i0      ] = c0;
        row[i0 + 256] = c1;
    }
    grid.sync();

    // ---------------- Phase 2: reduce + scatter ----------------
    const int gi = b * 256 + tid;
    if (gi < N) {
        unsigned int r = 0;
        #pragma unroll 8
        for (int y = 0; y < 32; ++y)
            r += partial[(size_t)y * N + gi];
        const float4 bb = bbox[gi];
        sortedBox[r]  = bb;
        sortedArea[r] = (bb.z - bb.x) * (bb.w - bb.y);
        mask[gi] = 0u;
    }
    grid.sync();

    // ---------------- Phase 3: suppress ----------------
    {
        float4* tile  = (float4*)smem_raw;
        float*  tarea = (float*)(smem_raw + 256 * 16);
        const int w = tid >> 6;               // wave id: k-quarter of i-tile
        const int l = tid & 63;

        for (int x = b; x < nTiles; x += (int)gridDim.x) {
            // decode triangular index: x = bj*(bj+1)/2 + bi, bi <= bj
            int bj = (int)((sqrtf(8.0f * (float)x + 1.0f) - 1.0f) * 0.5f);
            while ((bj + 1) * (bj + 2) / 2 <= x) ++bj;
            while (bj * (bj + 1) / 2 > x) --bj;
            const int bi = x - bj * (bj + 1) / 2;

            __syncthreads();                  // LDS reuse guard
            tile[tid]  = sortedBox[bi * 256 + tid];
            tarea[tid] = sortedArea[bi * 256 + tid];
            __syncthreads();

            float4 jb[4];
            float  aj[4];
            #pragma unroll
            for (int m = 0; m < 4; ++m) {
                const int j = bj * 256 + m * 64 + l;
                jb[m] = sortedBox[j];
                aj[m] = sortedArea[j];
            }

            unsigned int sup[4] = {0u, 0u, 0u, 0u};
            const int kbase = w * 64;

            if (bi < bj) {                    // uniform: no i<j predicate
                #pragma unroll 2
                for (int k = 0; k < 64; ++k) {
                    const float4 bo = tile[kbase + k];
                    const float  ai = tarea[kbase + k];
                    #pragma unroll
                    for (int m = 0; m < 4; ++m) {
                        const float iy1 = fmaxf(bo.x, jb[m].x);
                        const float ix1 = fmaxf(bo.y, jb[m].y);
                        const float iy2 = fminf(bo.z, jb[m].z);
                        const float ix2 = fminf(bo.w, jb[m].w);
                        const float ih  = fmaxf(iy2 - iy1, 0.0f);
                        const float iw  = fmaxf(ix2 - ix1, 0.0f);
                        const float inter = ih * iw;
                        const float s     = ai + aj[m];
                        // conservative wave-level gate: any exact hit has
                        // 1.69*inter - 0.69*s >= 0.0059*s >> rounding error
                        if (__any(fmaf(1.69f, inter, -0.69f * s) > 0.0f)) {
                            const float uni = s - inter;
                            sup[m] |= ((double)inter >= M_BOUND * (double)uni)
                                          ? 1u : 0u;
                        }
                    }
                }
            } else {                          // diagonal: predicate i<j
                #pragma unroll 2
                for (int k = 0; k < 64; ++k) {
                    const float4 bo = tile[kbase + k];
                    const float  ai = tarea[kbase + k];
                    const int    ig = kbase + k;
                    #pragma unroll
                    for (int m = 0; m < 4; ++m) {
                        const float iy1 = fmaxf(bo.x, jb[m].x);
                        const float ix1 = fmaxf(bo.y, jb[m].y);
                        const float iy2 = fminf(bo.z, jb[m].z);
                        const float ix2 = fminf(bo.w, jb[m].w);
                        const float ih  = fmaxf(iy2 - iy1, 0.0f);
                        const float iw  = fmaxf(ix2 - ix1, 0.0f);
                        const float inter = ih * iw;
                        const float s     = ai + aj[m];
                        if (__any(fmaf(1.69f, inter, -0.69f * s) > 0.0f)) {
                            const float uni = s - inter;
                            const bool hit =
                                ((double)inter >= M_BOUND * (double)uni) &&
                                (ig < m * 64 + l);
                            sup[m] |= hit ? 1u : 0u;
                        }
                    }
                }
            }

            #pragma unroll
            for (int m = 0; m < 4; ++m)
                if (sup[m]) atomicOr(&mask[bj * 256 + m * 64 + l], 1u);
        }
    }
    grid.sync();

    // ---------------- Phase 4: output ----------------
    // d_out layout: [N*4 floats boxes][N floats keep]
    if (gi < N) {
        const float s = (mask[gi] == 0u) ? 1.0f : 0.0f;
        const float4 bb = sortedBox[gi];
        float4 o;
        o.x = bb.x * s; o.y = bb.y * s; o.z = bb.z * s; o.w = bb.w * s;
        ((float4*)out)[gi] = o;
        out[N * 4 + gi] = s;
    }
}

extern "C" void kernel_launch(void* const* d_in, const int* in_sizes, int n_in,
                              void* d_out, int out_size, void* d_ws, size_t ws_size,
                              hipStream_t stream) {
    const float*  bbox  = (const float*)d_in[0];   // [1, N, 4] (y1,x1,y2,x2)
    const float*  score = (const float*)d_in[1];   // [1, N]
    int N = in_sizes[1];                           // 8192
    const int nb = N / 256;                        // 32
    int nTiles = nb * (nb + 1) / 2;                // 528

    char* ws = (char*)d_ws;
    float4*       sortedBox  = (float4*)ws;                             // N*16 B
    float*        sortedArea = (float*)(ws + (size_t)N * 16);           // N*4 B
    unsigned int* mask       = (unsigned int*)(ws + (size_t)N * 20);    // N*4 B
    unsigned int* partial    = (unsigned int*)(ws + (size_t)N * 24);    // 32*N*4 B
    float*        outp       = (float*)d_out;
    const float4* bbox4      = (const float4*)bbox;

    void* args[] = {(void*)&score, (void*)&bbox4, (void*)&partial,
                    (void*)&sortedBox, (void*)&sortedArea, (void*)&mask,
                    (void*)&outp, (void*)&N, (void*)&nTiles};

    // grid = (N/512)*(N/256) = 512 blocks (2/CU, co-resident); suppress
    // grid-strides the 528 tiles.
    hipLaunchCooperativeKernel((void*)nms_fused,
                               dim3((N / 512) * (N / 256)), dim3(256),
                               args, 0, stream);
}

// Round 8
// 39.513 us; speedup vs baseline: 4.2863x; 4.2863x over previous
//
#include <hip/hip_runtime.h>

// Exact decision boundary for  RN_f32(inter/uni) > (float)0.7 :
//   c = 0.7f = 0x3f333333, succ(c) = 0x3f333334 (even mantissa).
//   RN(x) > c  <=>  x >= M  where M = (c + succ(c))/2 (tie rounds to even
//   = succ(c) > c, so ">=" is correct).  M = 23488103 * 2^-25 (25 sig bits),
//   uni has <=24 sig bits  =>  M*(double)uni is EXACT, comparison is exact.
//   uni >= 2 always here (every box area >= 1), so uni==0 never occurs.
#define M_BOUND 0.7000000178813934326171875

__device__ __forceinline__ unsigned long long make_key(unsigned int sbits,
                                                       unsigned int idx) {
    // descending score, ascending index tie-break (stable argsort(-score))
    return (((unsigned long long)(~sbits)) << 32) | idx;
}

// ---------------------------------------------------------------------------
// Kernel A: partial rank counts, 2 i-keys per thread, LDS-staged key tile,
// no atomics.  grid = (N/512, N/256) = 512 blocks -> 2 blocks/CU.
// partial[y][i] = #{keys in y-tile < key_i}   (each cell written once)
// ---------------------------------------------------------------------------
__global__ __launch_bounds__(256)
void nms_rank_partial(const float* __restrict__ score,
                      unsigned int* __restrict__ partial, int N)
{
    __shared__ unsigned long long skeys[256];
    const int tid = threadIdx.x;
    const int y   = blockIdx.y;
    const int t   = y * 256 + tid;
    skeys[tid] = make_key(__float_as_uint(score[t]), (unsigned int)t);

    const int i0 = blockIdx.x * 512 + tid;
    const unsigned long long k0 = make_key(__float_as_uint(score[i0      ]), i0      );
    const unsigned long long k1 = make_key(__float_as_uint(score[i0 + 256]), i0 + 256);
    __syncthreads();

    unsigned int c0 = 0, c1 = 0;
    #pragma unroll 16
    for (int k = 0; k < 256; ++k) {
        const unsigned long long ok = skeys[k];
        c0 += (ok < k0) ? 1u : 0u;
        c1 += (ok < k1) ? 1u : 0u;
    }
    unsigned int* row = partial + (size_t)y * N;
    row[i0      ] = c0;
    row[i0 + 256] = c1;
}

// ---------------------------------------------------------------------------
// Kernel B: reduce partial ranks (32 independent coalesced loads), scatter
// box + area to sorted slot, zero the suppression mask.
// ---------------------------------------------------------------------------
__global__ __launch_bounds__(256)
void nms_scatter(const float4* __restrict__ bbox,
                 const unsigned int* __restrict__ partial,
                 float4* __restrict__ sortedBox,
                 float* __restrict__ sortedArea,
                 unsigned int* __restrict__ mask, int N)
{
    const int i = blockIdx.x * 256 + threadIdx.x;
    const int ny = N / 256;
    unsigned int r = 0;
    #pragma unroll 8
    for (int y = 0; y < ny; ++y)
        r += partial[(size_t)y * N + i];
    const float4 b = bbox[i];
    sortedBox[r]  = b;
    sortedArea[r] = (b.z - b.x) * (b.w - b.y);   // (y2-y1)*(x2-x1), once (as np)
    mask[i] = 0u;
}

// ---------------------------------------------------------------------------
// Kernel C: suppressed[j] |= any i<j with IoU > 0.7.
// Branchless f32 common path (~26 cyc/wave per (k,m)); the exact f64
// boundary compare runs only when a wave-level __any of the conservative
// f32 filter fires (s_cbranch_vccz skips it ~99% of the time).
// Filter safety: exact hit needs inter/s >= M/(1+M) ~= 0.41176; the filter
// fires at >= 0.69/1.69*(1 +- 2^-23) ~= 0.40828 -- margin 0.85% >> rounding,
// so no true hit is ever skipped.
// 1D triangular grid (bi <= bj); 4 waves split the i-tile (64 k's each);
// each lane owns 4 j's fed by one LDS broadcast.  Diagonal tiles keep the
// branchless i<j predicate.
// ---------------------------------------------------------------------------
__global__ __launch_bounds__(256)
void nms_suppress(const float4* __restrict__ sortedBox,
                  const float* __restrict__ sortedArea,
                  unsigned int* __restrict__ mask)
{
    // decode triangular index: x = bj*(bj+1)/2 + bi, bi <= bj
    const int x = blockIdx.x;
    int bj = (int)((sqrtf(8.0f * (float)x + 1.0f) - 1.0f) * 0.5f);
    while ((bj + 1) * (bj + 2) / 2 <= x) ++bj;
    while (bj * (bj + 1) / 2 > x) --bj;
    const int bi = x - bj * (bj + 1) / 2;

    __shared__ float4 tile[256];
    __shared__ float  tarea[256];
    const int tid = threadIdx.x;

    tile[tid]  = sortedBox[bi * 256 + tid];
    tarea[tid] = sortedArea[bi * 256 + tid];
    __syncthreads();

    const int w = tid >> 6;           // wave id: k-quarter of the i-tile
    const int l = tid & 63;
    const bool offdiag = (bi < bj);

    float4 jb[4];
    float  aj[4];
    #pragma unroll
    for (int m = 0; m < 4; ++m) {
        const int j = bj * 256 + m * 64 + l;
        jb[m] = sortedBox[j];
        aj[m] = sortedArea[j];
    }

    unsigned int sup[4] = {0u, 0u, 0u, 0u};
    const int kbase = w * 64;
    #pragma unroll 2
    for (int k = 0; k < 64; ++k) {
        const float4 bo = tile[kbase + k];
        const float  ai = tarea[kbase + k];
        const int    ig = kbase + k;          // local i index within tile
        #pragma unroll
        for (int m = 0; m < 4; ++m) {
            const float iy1 = fmaxf(bo.x, jb[m].x);
            const float ix1 = fmaxf(bo.y, jb[m].y);
            const float iy2 = fminf(bo.z, jb[m].z);
            const float ix2 = fminf(bo.w, jb[m].w);
            const float ih  = fmaxf(iy2 - iy1, 0.0f);
            const float iw  = fmaxf(ix2 - ix1, 0.0f);
            float inter = ih * iw;
            const float s = ai + aj[m];       // operands from memory: no fma
            // wave-level gate: cheap conservative filter, one scalar branch
            if (__any(fmaf(1.69f, inter, -0.69f * s) > 0.0f)) {
                asm volatile("" : "+v"(inter));   // block (s - ih*iw) -> fma
                const float uni = s - inter;
                const bool hit  = ((double)inter >= M_BOUND * (double)uni);
                const bool pred = offdiag || (ig < m * 64 + l);   // i<j on diag
                sup[m] |= (hit && pred) ? 1u : 0u;
            }
        }
    }
    #pragma unroll
    for (int m = 0; m < 4; ++m)
        if (sup[m]) atomicOr(&mask[bj * 256 + m * 64 + l], 1u);
}

// ---------------------------------------------------------------------------
// Kernel D: keep = !suppressed; write masked sorted boxes + keep flags.
// d_out layout: [N*4 floats boxes][N floats keep].
// ---------------------------------------------------------------------------
__global__ __launch_bounds__(256)
void nms_output(const float4* __restrict__ sortedBox,
                const unsigned int* __restrict__ mask,
                float* __restrict__ out, int N)
{
    const int j = blockIdx.x * 256 + threadIdx.x;
    const float s = (mask[j] == 0u) ? 1.0f : 0.0f;
    const float4 b = sortedBox[j];
    float4 o;
    o.x = b.x * s; o.y = b.y * s; o.z = b.z * s; o.w = b.w * s;
    ((float4*)out)[j] = o;
    out[N * 4 + j] = s;
}

extern "C" void kernel_launch(void* const* d_in, const int* in_sizes, int n_in,
                              void* d_out, int out_size, void* d_ws, size_t ws_size,
                              hipStream_t stream) {
    const float* bbox  = (const float*)d_in[0];   // [1, N, 4] (y1,x1,y2,x2)
    const float* score = (const float*)d_in[1];   // [1, N]
    const int N = in_sizes[1];                    // 8192
    const int nb = N / 256;                       // 32

    char* ws = (char*)d_ws;
    float4*       sortedBox  = (float4*)ws;                               // N*16 B
    float*        sortedArea = (float*)(ws + (size_t)N * 16);             // N*4 B
    unsigned int* mask       = (unsigned int*)(ws + (size_t)N * 20);      // N*4 B
    unsigned int* partial    = (unsigned int*)(ws + (size_t)N * 24);      // nb*N*4 B

    nms_rank_partial<<<dim3(N / 512, nb), 256, 0, stream>>>(score, partial, N);
    nms_scatter<<<nb, 256, 0, stream>>>((const float4*)bbox, partial,
                                        sortedBox, sortedArea, mask, N);
    nms_suppress<<<nb * (nb + 1) / 2, 256, 0, stream>>>(sortedBox, sortedArea,
                                                        mask);
    nms_output<<<nb, 256, 0, stream>>>(sortedBox, mask, (float*)d_out, N);
}